// Round 5
// baseline (997.515 us; speedup 1.0000x reference)
//
#include <hip/hip_runtime.h>

typedef unsigned short u16;
typedef unsigned int   u32;
typedef __bf16 bf16x8 __attribute__((ext_vector_type(8)));
typedef float  f32x4  __attribute__((ext_vector_type(4)));

// packed-weight regions (bf16 elements) in d_ws
#define OFF_W2  196608
#define OFF_W3  245760
#define OFF_TG  270336
#define OFF_TW1 335872
#define OFF_TW2 352256
#define NPACK   360448

__device__ __forceinline__ u16 f2bf(float f) {
  u32 u = __float_as_uint(f);
  u += 0x7FFFu + ((u >> 16) & 1u);   // RNE
  return (u16)(u >> 16);
}
__device__ __forceinline__ float bf2f(u16 s) { return __uint_as_float(((u32)s) << 16); }

union U4 { uint4 u; bf16x8 v; };
__device__ __forceinline__ bf16x8 ld_frag(const u16* p) {
  U4 t; t.u = *(const uint4*)p; return t.v;
}
__device__ __forceinline__ f32x4 mfma16(bf16x8 a, bf16x8 b, f32x4 c) {
  return __builtin_amdgcn_mfma_f32_16x16x32_bf16(a, b, c, 0, 0, 0);
}
__device__ __forceinline__ float swishf(float x) { return x / (1.f + __expf(-x)); }

// ---------------- weight repack: f32 row-major -> bf16 fragment order ----------------
// frag element (lane,i) of tile (nt,kt) = W[k][n], k = kt*32 + (lane>>4)*8 + i, n = nt*16 + (lane&15)
__global__ __launch_bounds__(256) void prep_pack(
    const float* __restrict__ eW1, const float* __restrict__ eW2,
    const float* __restrict__ eW3, const float* __restrict__ tgW1,
    const float* __restrict__ twW1, const float* __restrict__ twW2,
    u16* __restrict__ pk)
{
  int idx = blockIdx.x * 256 + threadIdx.x;
  if (idx >= NPACK) return;
  float v;
  if (idx < OFF_W2) {                 // exp_W1: [6][nt:8][kt:8][64][8]
    int i = idx & 7, lane = (idx >> 3) & 63, kt = (idx >> 9) & 7, nt = (idx >> 12) & 7, e = idx >> 15;
    int k = kt*32 + (lane>>4)*8 + i, n = nt*16 + (lane & 15);
    v = eW1[(e*256 + k)*128 + n];
  } else if (idx < OFF_W3) {          // exp_W2: [6][nt:4][kt:4][64][8]
    int j = idx - OFF_W2;
    int i = j & 7, lane = (j >> 3) & 63, kt = (j >> 9) & 3, nt = (j >> 11) & 3, e = j >> 13;
    int k = kt*32 + (lane>>4)*8 + i, n = nt*16 + (lane & 15);
    v = eW2[(e*128 + k)*64 + n];
  } else if (idx < OFF_TG) {          // exp_W3: [6][nt:4][kt:2][64][8]
    int j = idx - OFF_W3;
    int i = j & 7, lane = (j >> 3) & 63, kt = (j >> 9) & 1, nt = (j >> 10) & 3, e = j >> 12;
    int k = kt*32 + (lane>>4)*8 + i, n = nt*16 + (lane & 15);
    v = eW3[(e*64 + k)*64 + n];
  } else if (idx < OFF_TW1) {         // tg_W1: [4][nt:4][kt:8][64][8]
    int j = idx - OFF_TG;
    int i = j & 7, lane = (j >> 3) & 63, kt = (j >> 9) & 7, nt = (j >> 12) & 3, t = j >> 14;
    int k = kt*32 + (lane>>4)*8 + i, n = nt*16 + (lane & 15);
    v = tgW1[(t*256 + k)*64 + n];
  } else if (idx < OFF_TW2) {         // tw_W1: [4][nt:4][kt:2][64][8]
    int j = idx - OFF_TW1;
    int i = j & 7, lane = (j >> 3) & 63, kt = (j >> 9) & 1, nt = (j >> 10) & 3, t = j >> 12;
    int k = kt*32 + (lane>>4)*8 + i, n = nt*16 + (lane & 15);
    v = twW1[(t*64 + k)*64 + n];
  } else {                            // tw_W2: [4][nt:2][kt:2][64][8]
    int j = idx - OFF_TW2;
    int i = j & 7, lane = (j >> 3) & 63, kt = (j >> 9) & 1, nt = (j >> 10) & 1, t = j >> 11;
    int k = kt*32 + (lane>>4)*8 + i, n = nt*16 + (lane & 15);
    v = twW2[(t*64 + k)*32 + n];
  }
  pk[idx] = f2bf(v);
}

// ---------------- fused main kernel: 64 rows/block, loops 4 tasks ----------------
// __launch_bounds__(256, 2): empirical allocator budget = 256/min_waves VGPRs on this
// toolchain (r1/r4: min2->128 spill-free, r2/r3: min4->64 -> 440 MB spills). Occupancy is
// 2 waves/SIMD (arch+acc regs), so 2 blocks/CU; LDS 76 KB also caps at 2 blocks/CU.
// 64 rows/block halves barriers-per-row vs r4 (latency/barrier-bound per r4 counters).
__global__ __launch_bounds__(256, 2) void home_main(
    const float* __restrict__ zs, const float* __restrict__ zg0, const float* __restrict__ zg1,
    const float* __restrict__ fgA, const float* __restrict__ fgB,
    const float* __restrict__ tgW2, const float* __restrict__ tgb1, const float* __restrict__ tgb2,
    const float* __restrict__ eb1, const float* __restrict__ eb2, const float* __restrict__ eb3,
    const float* __restrict__ lns, const float* __restrict__ lnb,
    const float* __restrict__ sgW, const float* __restrict__ sgb,
    const float* __restrict__ twb1, const float* __restrict__ twb2,
    const float* __restrict__ twW3, const float* __restrict__ twb3,
    const u16* __restrict__ pk, float* __restrict__ out)
{
  __shared__ __align__(16) u16   cmfrag[4*8*64*8];   // 32 KB  cm A-frags [mt4][kt8][64][8]; holds pre-z then gated
  __shared__ __align__(16) float region1[4416];      // 17.25 KB: {fgAs[2112]+fgBs[2304]} | fbuf[64][68] | th1frag
  __shared__ __align__(16) u16   h1frag[4*4*64*8];   // 16 KB  h1 A-frags [mt4][kt4][64][8]
  __shared__ __align__(16) u16   h2frag[4*2*64*8];   //  8 KB  h2 A-frags ; alias aggfrag
  __shared__ __align__(16) float gwbuf[256];         //  1 KB  softmax gate weights [64][4]
  __shared__ __align__(16) float arrp[128];          //  0.5 KB tower partials [2][64]
  __shared__ __align__(16) float smallw[320];        //  1.25 KB tg_W2^T swizzled

  float* fgAs    = region1;          // [q:8][264]
  float* fgBs    = region1 + 2112;   // [rr:8][q:8][36]
  float* fbuf    = region1;          // [64][68]  (gh, then e_pre)
  u16*   th1frag = (u16*)region1;    // [mt4][kt2][64][8]
  u16*   aggfrag = h2frag;           // [mt4][kt2][64][8]

  const int tid  = threadIdx.x;
  const int lane = tid & 63;
  const int wid  = tid >> 6;       // wave 0..3
  const int r8   = tid >> 3;       // row 0..31 (per half)
  const int q    = tid & 7;        // eighth of the 256-d feature / col-slice
  const int rowBase = blockIdx.x * 64;
  const int rl   = (lane >> 4) * 4;   // C-layout row offset
  const int l15  = lane & 15;
  const f32x4 fz = {0.f, 0.f, 0.f, 0.f};

  #pragma unroll 1
  for (int pair = 0; pair < 2; ++pair) {
    const int g = pair;
    #pragma unroll 1
    for (int sub = 0; sub < 2; ++sub) {
      const int t = pair * 2 + sub;

      // ---------- stage cm_pre (bf16) into cmfrag + fgA/fgB/tgW2 into LDS ----------
      {
        const int rs = tid >> 2, p = tid & 3;
        const int mt_s = rs >> 4, r15_s = rs & 15;
        const float* s0 = zs + (size_t)(rowBase + rs)*128 + p*32;
        const float* s1 = (pair ? zg1 : zg0) + (size_t)(rowBase + rs)*128 + p*32;
        #pragma unroll
        for (int h = 0; h < 4; ++h) {
          float4 a = ((const float4*)s0)[2*h], b4 = ((const float4*)s0)[2*h+1];
          uint4 wv;
          wv.x = (u32)f2bf(a.x)  | ((u32)f2bf(a.y)  << 16);
          wv.y = (u32)f2bf(a.z)  | ((u32)f2bf(a.w)  << 16);
          wv.z = (u32)f2bf(b4.x) | ((u32)f2bf(b4.y) << 16);
          wv.w = (u32)f2bf(b4.z) | ((u32)f2bf(b4.w) << 16);
          *(uint4*)&cmfrag[((mt_s*8 + p)*64 + r15_s + 16*h)*8] = wv;
        }
        #pragma unroll
        for (int h = 0; h < 4; ++h) {
          float4 a = ((const float4*)s1)[2*h], b4 = ((const float4*)s1)[2*h+1];
          uint4 wv;
          wv.x = (u32)f2bf(a.x)  | ((u32)f2bf(a.y)  << 16);
          wv.y = (u32)f2bf(a.z)  | ((u32)f2bf(a.w)  << 16);
          wv.z = (u32)f2bf(b4.x) | ((u32)f2bf(b4.y) << 16);
          wv.w = (u32)f2bf(b4.z) | ((u32)f2bf(b4.w) << 16);
          *(uint4*)&cmfrag[((mt_s*8 + 4 + p)*64 + r15_s + 16*h)*8] = wv;
        }
      }
      #pragma unroll
      for (int u = 0; u < 8; ++u) {
        int idx = tid + u*256;
        int c = idx >> 3, rr = idx & 7;
        fgAs[(c>>5)*264 + (c&31)*8 + rr] = fgA[t*2048 + idx];
      }
      #pragma unroll
      for (int u = 0; u < 8; ++u) {
        int idx = tid + u*256;
        int rr = idx >> 8, c = idx & 255;
        fgBs[rr*288 + (c>>5)*36 + (c&31)] = fgB[t*2048 + idx];
      }
      {
        int e = tid >> 6, c = tid & 63, half = c >> 5, cl = c & 31;
        smallw[(e*2 + half)*36 + cl] = tgW2[t*256 + c*4 + e];
      }
      __syncthreads();   // A

      // ---------- feature gate (in-place on cmfrag), loop row halves ----------
      #pragma unroll 1
      for (int rh = 0; rh < 2; ++rh) {
        const int row = rh*32 + r8;
        const int mtg = row >> 4, r15g = row & 15;
        u32 zz[16];
        #pragma unroll
        for (int h = 0; h < 4; ++h) {
          uint4 wv = *(const uint4*)&cmfrag[((mtg*8 + q)*64 + r15g + 16*h)*8];
          zz[4*h] = wv.x; zz[4*h+1] = wv.y; zz[4*h+2] = wv.z; zz[4*h+3] = wv.w;
        }
        float acc[8];
        #pragma unroll
        for (int rr = 0; rr < 8; ++rr) acc[rr] = 0.f;
        const float* Ap = fgAs + q*264;
        #pragma unroll
        for (int jf = 0; jf < 8; ++jf) {
          u32 p0 = zz[2*jf], p1 = zz[2*jf+1];
          float zc[4] = { bf2f((u16)p0), bf2f((u16)(p0>>16)), bf2f((u16)p1), bf2f((u16)(p1>>16)) };
          #pragma unroll
          for (int u = 0; u < 4; ++u) {
            const float4* ar = (const float4*)(Ap + (jf*4 + u)*8);
            float4 lo = ar[0], hi = ar[1];
            acc[0] += zc[u]*lo.x; acc[1] += zc[u]*lo.y; acc[2] += zc[u]*lo.z; acc[3] += zc[u]*lo.w;
            acc[4] += zc[u]*hi.x; acc[5] += zc[u]*hi.y; acc[6] += zc[u]*hi.z; acc[7] += zc[u]*hi.w;
          }
        }
        #pragma unroll
        for (int rr = 0; rr < 8; ++rr) {
          acc[rr] += __shfl_xor(acc[rr], 1);
          acc[rr] += __shfl_xor(acc[rr], 2);
          acc[rr] += __shfl_xor(acc[rr], 4);
        }
        #pragma unroll
        for (int h = 0; h < 4; ++h) {
          u16 pk8[8];
          #pragma unroll
          for (int half = 0; half < 2; ++half) {
            const float* bp = fgBs + q*36 + h*8 + half*4;
            float l0=0.f, l1=0.f, l2=0.f, l3=0.f;
            #pragma unroll
            for (int rr = 0; rr < 8; ++rr) {
              float4 b4 = *(const float4*)(bp + rr*288);
              l0 += acc[rr]*b4.x; l1 += acc[rr]*b4.y; l2 += acc[rr]*b4.z; l3 += acc[rr]*b4.w;
            }
            int zi = h*4 + half*2;
            u32 p0 = zz[zi], p1 = zz[zi+1];
            float zv[4] = { bf2f((u16)p0), bf2f((u16)(p0>>16)), bf2f((u16)p1), bf2f((u16)(p1>>16)) };
            float lg[4] = { l0, l1, l2, l3 };
            #pragma unroll
            for (int u = 0; u < 4; ++u) {
              float gate = 2.f / (1.f + __expf(-lg[u]));
              pk8[half*4 + u] = f2bf(zv[u] * gate);
            }
          }
          uint4 wv;
          wv.x = (u32)pk8[0] | ((u32)pk8[1] << 16);
          wv.y = (u32)pk8[2] | ((u32)pk8[3] << 16);
          wv.z = (u32)pk8[4] | ((u32)pk8[5] << 16);
          wv.w = (u32)pk8[6] | ((u32)pk8[7] << 16);
          *(uint4*)&cmfrag[((mtg*8 + q)*64 + r15g + 16*h)*8] = wv;
        }
      }
      __syncthreads();   // B

      // ---------- task gate layer1: gh = swish(cm @ tg_W1 + b); wave w owns n-tile w ----------
      {
        f32x4 accg[4] = { fz, fz, fz, fz };
        const u16* wp = pk + OFF_TG + ((t*4 + wid)*8)*512 + lane*8;
        #pragma unroll
        for (int kt = 0; kt < 8; ++kt) {
          bf16x8 bfr = ld_frag(wp + kt*512);
          #pragma unroll
          for (int mt = 0; mt < 4; ++mt) {
            bf16x8 afr = ld_frag(&cmfrag[((mt*8 + kt)*64 + lane)*8]);
            accg[mt] = mfma16(afr, bfr, accg[mt]);
          }
        }
        int colg = wid*16 + l15;
        float bias = tgb1[t*64 + colg];
        #pragma unroll
        for (int mt = 0; mt < 4; ++mt)
          #pragma unroll
          for (int rr = 0; rr < 4; ++rr)
            fbuf[(mt*16 + rl + rr)*68 + colg] = swishf(accg[mt][rr] + bias);
      }
      __syncthreads();   // C

      // ---------- task gate layer2 + softmax (lanes q,q+4 split the 64-dim dot) ----------
      {
        const int e = q & 3, hf = q >> 2;
        #pragma unroll 1
        for (int rh = 0; rh < 2; ++rh) {
          int row = rh*32 + r8;
          float part = 0.f;
          #pragma unroll
          for (int cj = 0; cj < 8; ++cj) {
            float4 g4 = *(const float4*)&fbuf[row*68 + hf*32 + cj*4];
            float4 w4 = *(const float4*)&smallw[(e*2 + hf)*36 + cj*4];
            part += g4.x*w4.x + g4.y*w4.y + g4.z*w4.z + g4.w*w4.w;
          }
          part += __shfl_xor(part, 4);
          float logit = part + tgb2[t*4 + e];
          float mx = fmaxf(logit, __shfl_xor(logit, 1));
          mx = fmaxf(mx, __shfl_xor(mx, 2));
          float ex = __expf(logit - mx);
          float sm = ex + __shfl_xor(ex, 1);
          sm += __shfl_xor(sm, 2);
          if (q < 4) gwbuf[row*4 + q] = ex / sm;
        }
      }
      // NO barrier: gwbuf first read (LN el=0) is 3 barriers away; GEMM1 touches only h1frag/cmfrag.

      // ---------- expert loop ----------
      float agg[16];
      #pragma unroll
      for (int c = 0; c < 16; ++c) agg[c] = 0.f;

      #pragma unroll 1
      for (int el = 0; el < 4; ++el) {
        const int ei = (el < 2) ? el : (el + 2*g);

        // GEMM1: cm(64x256) @ W1(256x128); wave owns n-tiles 2w,2w+1
        f32x4 acc1[4][2];
        #pragma unroll
        for (int mt = 0; mt < 4; ++mt) { acc1[mt][0] = fz; acc1[mt][1] = fz; }
        {
          const u16* w1p = pk + ((ei*8 + 2*wid)*8)*512 + lane*8;
          #pragma unroll
          for (int kt = 0; kt < 8; ++kt) {
            bf16x8 b0 = ld_frag(w1p + kt*512);
            bf16x8 b1 = ld_frag(w1p + 4096 + kt*512);
            #pragma unroll
            for (int mt = 0; mt < 4; ++mt) {
              bf16x8 a = ld_frag(&cmfrag[((mt*8 + kt)*64 + lane)*8]);
              acc1[mt][0] = mfma16(a, b0, acc1[mt][0]);
              acc1[mt][1] = mfma16(a, b1, acc1[mt][1]);
            }
          }
        }
        #pragma unroll
        for (int nn = 0; nn < 2; ++nn) {
          int col = (2*wid + nn)*16 + l15;
          float bias = eb1[ei*128 + col];
          int kt2 = col >> 5, h2 = (col >> 3) & 3, i2 = col & 7;
          #pragma unroll
          for (int mt = 0; mt < 4; ++mt)
            #pragma unroll
            for (int rr = 0; rr < 4; ++rr)
              h1frag[((mt*4 + kt2)*64 + rl + rr + 16*h2)*8 + i2] = f2bf(swishf(acc1[mt][nn][rr] + bias));
        }
        __syncthreads();  // E1

        // GEMM2: h1(64x128) @ W2(128x64); wave owns n-tile w
        f32x4 acc2[4] = { fz, fz, fz, fz };
        {
          const u16* w2p = pk + OFF_W2 + ((ei*4 + wid)*4)*512 + lane*8;
          #pragma unroll
          for (int kt = 0; kt < 4; ++kt) {
            bf16x8 b0 = ld_frag(w2p + kt*512);
            #pragma unroll
            for (int mt = 0; mt < 4; ++mt) {
              bf16x8 a = ld_frag(&h1frag[((mt*4 + kt)*64 + lane)*8]);
              acc2[mt] = mfma16(a, b0, acc2[mt]);
            }
          }
        }
        {
          int col = wid*16 + l15;
          float bias = eb2[ei*64 + col];
          int kt2 = col >> 5, h2 = (col >> 3) & 3, i2 = col & 7;
          #pragma unroll
          for (int mt = 0; mt < 4; ++mt)
            #pragma unroll
            for (int rr = 0; rr < 4; ++rr)
              h2frag[((mt*2 + kt2)*64 + rl + rr + 16*h2)*8 + i2] = f2bf(swishf(acc2[mt][rr] + bias));
        }
        __syncthreads();  // E2

        // GEMM3: h2(64x64) @ W3(64x64) -> e_pre into fbuf
        f32x4 acc3[4] = { fz, fz, fz, fz };
        {
          const u16* w3p = pk + OFF_W3 + ((ei*4 + wid)*2)*512 + lane*8;
          #pragma unroll
          for (int kt = 0; kt < 2; ++kt) {
            bf16x8 b0 = ld_frag(w3p + kt*512);
            #pragma unroll
            for (int mt = 0; mt < 4; ++mt) {
              bf16x8 a = ld_frag(&h2frag[((mt*2 + kt)*64 + lane)*8]);
              acc3[mt] = mfma16(a, b0, acc3[mt]);
            }
          }
        }
        {
          int col = wid*16 + l15;
          float bias = eb3[ei*64 + col];
          #pragma unroll
          for (int mt = 0; mt < 4; ++mt)
            #pragma unroll
            for (int rr = 0; rr < 4; ++rr)
              fbuf[(mt*16 + rl + rr)*68 + col] = acc3[mt][rr] + bias;
        }
        __syncthreads();  // E3

        // LayerNorm + self-gate diag + weighted aggregate; unrolled row halves (static agg idx)
        #pragma unroll
        for (int rh = 0; rh < 2; ++rh) {
          const int row = rh*32 + r8;
          float v[8];
          float4 fa = *(const float4*)&fbuf[row*68 + q*8];
          float4 fb = *(const float4*)&fbuf[row*68 + q*8 + 4];
          v[0]=fa.x; v[1]=fa.y; v[2]=fa.z; v[3]=fa.w;
          v[4]=fb.x; v[5]=fb.y; v[6]=fb.z; v[7]=fb.w;
          float s1 = 0.f;
          #pragma unroll
          for (int c = 0; c < 8; ++c) s1 += v[c];
          s1 += __shfl_xor(s1, 1); s1 += __shfl_xor(s1, 2); s1 += __shfl_xor(s1, 4);
          float mu = s1 * (1.f/64.f);
          float s2 = 0.f;
          #pragma unroll
          for (int c = 0; c < 8; ++c) { float d = v[c] - mu; s2 += d*d; }
          s2 += __shfl_xor(s2, 1); s2 += __shfl_xor(s2, 2); s2 += __shfl_xor(s2, 4);
          float rs = rsqrtf(s2 * (1.f/64.f) + 1e-5f);
          const float* lsp = lns + ei*64 + q*8;
          const float* lbp = lnb + ei*64 + q*8;
          const float* sgp = sgW + (t*64 + q*8)*4 + el;
          float swp = 0.f;
          #pragma unroll
          for (int c = 0; c < 8; ++c) {
            float eh = (v[c] - mu) * rs * lsp[c] + lbp[c];
            v[c] = eh;
            swp += eh * sgp[c*4];
          }
          swp += __shfl_xor(swp, 1); swp += __shfl_xor(swp, 2); swp += __shfl_xor(swp, 4);
          swp += sgb[t*4 + el];
          float fac = swp * gwbuf[row*4 + el];
          #pragma unroll
          for (int c = 0; c < 8; ++c) agg[rh*8 + c] += v[c] * fac;
        }
        // no barrier: next GEMM1 writes h1frag (disjoint from fbuf/gwbuf); E1 orders it.
      }  // expert loop

      // ---------- tower via MFMA: agg(64x64) @ W1(64x64) -> swish -> @ W2(64x32) -> swish -> @ w3 ----------
      #pragma unroll
      for (int rh = 0; rh < 2; ++rh) {
        const int row = rh*32 + r8;
        const int mtg = row >> 4, r15g = row & 15;
        uint4 wv;
        wv.x = (u32)f2bf(agg[rh*8+0]) | ((u32)f2bf(agg[rh*8+1]) << 16);
        wv.y = (u32)f2bf(agg[rh*8+2]) | ((u32)f2bf(agg[rh*8+3]) << 16);
        wv.z = (u32)f2bf(agg[rh*8+4]) | ((u32)f2bf(agg[rh*8+5]) << 16);
        wv.w = (u32)f2bf(agg[rh*8+6]) | ((u32)f2bf(agg[rh*8+7]) << 16);
        *(uint4*)&aggfrag[((mtg*2 + (q>>2))*64 + r15g + 16*(q&3))*8] = wv;
      }
      __syncthreads();  // F

      {
        // T1: wave w owns n-tile w of 64
        f32x4 at1[4] = { fz, fz, fz, fz };
        const u16* tw1p = pk + OFF_TW1 + ((t*4 + wid)*2)*512 + lane*8;
        #pragma unroll
        for (int kt = 0; kt < 2; ++kt) {
          bf16x8 b0 = ld_frag(tw1p + kt*512);
          #pragma unroll
          for (int mt = 0; mt < 4; ++mt) {
            bf16x8 a = ld_frag(&aggfrag[((mt*2 + kt)*64 + lane)*8]);
            at1[mt] = mfma16(a, b0, at1[mt]);
          }
        }
        int colT = wid*16 + l15;
        float bias = twb1[t*64 + colT];
        int ktT = colT >> 5, hT = (colT >> 3) & 3, iT = colT & 7;
        #pragma unroll
        for (int mt = 0; mt < 4; ++mt)
          #pragma unroll
          for (int rr = 0; rr < 4; ++rr)
            th1frag[((mt*2 + ktT)*64 + rl + rr + 16*hT)*8 + iT] = f2bf(swishf(at1[mt][rr] + bias));
      }
      __syncthreads();  // G

      if (wid < 2) {
        // T2: waves 0,1 own the two 16-col tiles of 32
        f32x4 at2[4] = { fz, fz, fz, fz };
        const u16* tw2p = pk + OFF_TW2 + ((t*2 + wid)*2)*512 + lane*8;
        #pragma unroll
        for (int kt = 0; kt < 2; ++kt) {
          bf16x8 b0 = ld_frag(tw2p + kt*512);
          #pragma unroll
          for (int mt = 0; mt < 4; ++mt) {
            bf16x8 a = ld_frag(&th1frag[((mt*2 + kt)*64 + lane)*8]);
            at2[mt] = mfma16(a, b0, at2[mt]);
          }
        }
        int colU = wid*16 + l15;
        float b2  = twb2[t*32 + colU];
        float w3v = twW3[t*32 + colU];
        float px[16];
        #pragma unroll
        for (int mt = 0; mt < 4; ++mt)
          #pragma unroll
          for (int rr = 0; rr < 4; ++rr)
            px[mt*4 + rr] = swishf(at2[mt][rr] + b2) * w3v;
        #pragma unroll
        for (int k = 0; k < 16; ++k) {
          px[k] += __shfl_xor(px[k], 1);
          px[k] += __shfl_xor(px[k], 2);
          px[k] += __shfl_xor(px[k], 4);
          px[k] += __shfl_xor(px[k], 8);
        }
        if (l15 == 0) {
          #pragma unroll
          for (int mt = 0; mt < 4; ++mt)
            #pragma unroll
            for (int rr = 0; rr < 4; ++rr)
              arrp[wid*64 + mt*16 + rl + rr] = px[mt*4 + rr];
        }
      }
      __syncthreads();  // H

      if (tid < 64) {
        float x = arrp[tid] + arrp[64 + tid] + twb3[t];
        out[(size_t)(rowBase + tid)*4 + t] = 1.f / (1.f + __expf(-x));
      }
      // NO barrier I: next sub's staging touches cmfrag/region1/smallw, whose last
      // readers (GEMM1 el3 / T2) all complete before barrier H; arrp untouched by staging.
    }
  }
}

extern "C" void kernel_launch(void* const* d_in, const int* in_sizes, int n_in,
                              void* d_out, int out_size, void* d_ws, size_t ws_size,
                              hipStream_t stream)
{
  (void)in_sizes; (void)n_in; (void)out_size; (void)ws_size;
  const float* zs   = (const float*)d_in[0];
  const float* zg0  = (const float*)d_in[1];
  const float* zg1  = (const float*)d_in[2];
  // d_in[3] = v : unused by the reference
  const float* eW1  = (const float*)d_in[4];
  const float* eb1  = (const float*)d_in[5];
  const float* eW2  = (const float*)d_in[6];
  const float* eb2  = (const float*)d_in[7];
  const float* eW3  = (const float*)d_in[8];
  const float* eb3  = (const float*)d_in[9];
  const float* lns  = (const float*)d_in[10];
  const float* lnb  = (const float*)d_in[11];
  const float* fgA  = (const float*)d_in[12];
  const float* fgB  = (const float*)d_in[13];
  const float* tgW1 = (const float*)d_in[14];
  const float* tgb1 = (const float*)d_in[15];
  const float* tgW2 = (const float*)d_in[16];
  const float* tgb2 = (const float*)d_in[17];
  const float* sgW  = (const float*)d_in[18];
  const float* sgb  = (const float*)d_in[19];
  const float* twW1 = (const float*)d_in[20];
  const float* twb1 = (const float*)d_in[21];
  const float* twW2 = (const float*)d_in[22];
  const float* twb2 = (const float*)d_in[23];
  const float* twW3 = (const float*)d_in[24];
  const float* twb3 = (const float*)d_in[25];

  u16* pkw = (u16*)d_ws;          // needs 720896 B
  float* outp = (float*)d_out;

  prep_pack<<<(NPACK + 255)/256, 256, 0, stream>>>(eW1, eW2, eW3, tgW1, twW1, twW2, pkw);
  home_main<<<65536/64, 256, 0, stream>>>(zs, zg0, zg1, fgA, fgB, tgW2, tgb1, tgb2,
      eb1, eb2, eb3, lns, lnb, sgW, sgb, twb1, twb2, twW3, twb3,
      pkw, outp);
}

// Round 6
// 451.324 us; speedup vs baseline: 2.2102x; 2.2102x over previous
//
#include <hip/hip_runtime.h>

typedef unsigned short u16;
typedef unsigned int   u32;
typedef __bf16 bf16x8 __attribute__((ext_vector_type(8)));
typedef float  f32x4  __attribute__((ext_vector_type(4)));

// packed-weight regions (bf16 elements) in d_ws
#define OFF_W2  196608
#define OFF_W3  245760
#define OFF_TG  270336
#define OFF_TW1 335872
#define OFF_TW2 352256
#define NPACK   360448

__device__ __forceinline__ u16 f2bf(float f) {
  u32 u = __float_as_uint(f);
  u += 0x7FFFu + ((u >> 16) & 1u);   // RNE
  return (u16)(u >> 16);
}
__device__ __forceinline__ float bf2f(u16 s) { return __uint_as_float(((u32)s) << 16); }

union U4 { uint4 u; bf16x8 v; };
__device__ __forceinline__ bf16x8 ld_frag(const u16* p) {
  U4 t; t.u = *(const uint4*)p; return t.v;
}
__device__ __forceinline__ f32x4 mfma16(bf16x8 a, bf16x8 b, f32x4 c) {
  return __builtin_amdgcn_mfma_f32_16x16x32_bf16(a, b, c, 0, 0, 0);
}
__device__ __forceinline__ float swishf(float x) { return x / (1.f + __expf(-x)); }

// ---------------- weight repack: f32 row-major -> bf16 fragment order ----------------
// frag element (lane,i) of tile (nt,kt) = W[k][n], k = kt*32 + (lane>>4)*8 + i, n = nt*16 + (lane&15)
__global__ __launch_bounds__(256) void prep_pack(
    const float* __restrict__ eW1, const float* __restrict__ eW2,
    const float* __restrict__ eW3, const float* __restrict__ tgW1,
    const float* __restrict__ twW1, const float* __restrict__ twW2,
    u16* __restrict__ pk)
{
  int idx = blockIdx.x * 256 + threadIdx.x;
  if (idx >= NPACK) return;
  float v;
  if (idx < OFF_W2) {                 // exp_W1: [6][nt:8][kt:8][64][8]
    int i = idx & 7, lane = (idx >> 3) & 63, kt = (idx >> 9) & 7, nt = (idx >> 12) & 7, e = idx >> 15;
    int k = kt*32 + (lane>>4)*8 + i, n = nt*16 + (lane & 15);
    v = eW1[(e*256 + k)*128 + n];
  } else if (idx < OFF_W3) {          // exp_W2: [6][nt:4][kt:4][64][8]
    int j = idx - OFF_W2;
    int i = j & 7, lane = (j >> 3) & 63, kt = (j >> 9) & 3, nt = (j >> 11) & 3, e = j >> 13;
    int k = kt*32 + (lane>>4)*8 + i, n = nt*16 + (lane & 15);
    v = eW2[(e*128 + k)*64 + n];
  } else if (idx < OFF_TG) {          // exp_W3: [6][nt:4][kt:2][64][8]
    int j = idx - OFF_W3;
    int i = j & 7, lane = (j >> 3) & 63, kt = (j >> 9) & 1, nt = (j >> 10) & 3, e = j >> 12;
    int k = kt*32 + (lane>>4)*8 + i, n = nt*16 + (lane & 15);
    v = eW3[(e*64 + k)*64 + n];
  } else if (idx < OFF_TW1) {         // tg_W1: [4][nt:4][kt:8][64][8]
    int j = idx - OFF_TG;
    int i = j & 7, lane = (j >> 3) & 63, kt = (j >> 9) & 7, nt = (j >> 12) & 3, t = j >> 14;
    int k = kt*32 + (lane>>4)*8 + i, n = nt*16 + (lane & 15);
    v = tgW1[(t*256 + k)*64 + n];
  } else if (idx < OFF_TW2) {         // tw_W1: [4][nt:4][kt:2][64][8]
    int j = idx - OFF_TW1;
    int i = j & 7, lane = (j >> 3) & 63, kt = (j >> 9) & 1, nt = (j >> 10) & 3, t = j >> 12;
    int k = kt*32 + (lane>>4)*8 + i, n = nt*16 + (lane & 15);
    v = twW1[(t*64 + k)*64 + n];
  } else {                            // tw_W2: [4][nt:2][kt:2][64][8]
    int j = idx - OFF_TW2;
    int i = j & 7, lane = (j >> 3) & 63, kt = (j >> 9) & 1, nt = (j >> 10) & 1, t = j >> 11;
    int k = kt*32 + (lane>>4)*8 + i, n = nt*16 + (lane & 15);
    v = twW2[(t*64 + k)*32 + n];
  }
  pk[idx] = f2bf(v);
}

// ---------------- fused main kernel: 32 rows/block, loops 4 tasks ----------------
// Occupancy/VGPR calibration (this toolchain, measured r1-r5):
//   arch-VGPR budget = 256 / min_waves_per_eu:  min2->128, min3->~85, min4->64.
//   Total pool 512/SIMD incl. MFMA acc regs: r4 (128 arch + acc) -> only 2 waves/SIMD (occ 24%).
//   min4 (64 arch) spills ~440 MB (r2/r3). Sweet spot: min3 -> 85 arch + ~32 acc <= 128 total
//   -> 4 waves/SIMD, matching the LDS cap (40 KB -> 4 blocks/CU). No zsh regs (z staged
//   straight to LDS frags) keeps peak live state ~55-60 < 85 -> no spill.
__global__ __launch_bounds__(256, 3) void home_main(
    const float* __restrict__ zs, const float* __restrict__ zg0, const float* __restrict__ zg1,
    const float* __restrict__ fgA, const float* __restrict__ fgB,
    const float* __restrict__ tgW2, const float* __restrict__ tgb1, const float* __restrict__ tgb2,
    const float* __restrict__ eb1, const float* __restrict__ eb2, const float* __restrict__ eb3,
    const float* __restrict__ lns, const float* __restrict__ lnb,
    const float* __restrict__ sgW, const float* __restrict__ sgb,
    const float* __restrict__ twb1, const float* __restrict__ twb2,
    const float* __restrict__ twW3, const float* __restrict__ twb3,
    const u16* __restrict__ pk, float* __restrict__ out)
{
  __shared__ __align__(16) u16   cmfrag[2*8*64*8];       // 16 KB  cm A-frags [mt2][kt8][64][8]; pre-z then gated
  __shared__ __align__(16) u16   h1frag[2*4*64*8 + 512]; // 9 KB   h1 A-frags ; alias fgBs (f32[2304])
  __shared__ __align__(16) u16   h2frag[2*2*64*8];       // 4 KB   h2 A-frags ; alias aggfrag
  __shared__ __align__(16) float fbuf[32*72];            // 9 KB   gh / e_pre ; alias fgAs, th1frag
  __shared__ __align__(16) float gwbuf[128];             //  gate weights ; alias tower partials
  __shared__ __align__(16) float smallw[320];            //  tg_W2^T swizzled

  float* fgAs    = fbuf;            // [q:8][264] : c_local*8 + rr
  float* fgBs    = (float*)h1frag;  // [rr:8][q:8][36] : c_local
  u16*   aggfrag = h2frag;          // [mt2][kt2][64][8]
  u16*   th1frag = (u16*)fbuf;      // [mt2][kt2][64][8]
  float* arrp    = gwbuf;           // [2][32] tower partials

  const int tid  = threadIdx.x;
  const int lane = tid & 63;
  const int wid  = tid >> 6;       // wave 0..3
  const int r    = tid >> 3;       // row 0..31
  const int q    = tid & 7;        // eighth of the 256-d feature
  const int rowBase = blockIdx.x * 32;
  const int mt_r = r >> 4, r15 = r & 15;
  const int rl   = (lane >> 4) * 4;   // C-layout row offset
  const int l15  = lane & 15;
  const f32x4 fz = {0.f, 0.f, 0.f, 0.f};

  #pragma unroll 1
  for (int pair = 0; pair < 2; ++pair) {
    const int g = pair;
    #pragma unroll 1
    for (int sub = 0; sub < 2; ++sub) {
      const int t = pair * 2 + sub;

      // ---------- stage cm_pre (bf16) directly into cmfrag + fgA/fgB/tgW2 into LDS ----------
      {
        // thread (r,q): 32 cols q*32..q*32+31 of row r; q<4 from zs, q>=4 from zg
        const float* zsrc = (q < 4)
          ? (zs + (size_t)(rowBase + r) * 128 + q * 32)
          : ((pair ? zg1 : zg0) + (size_t)(rowBase + r) * 128 + (q - 4) * 32);
        #pragma unroll
        for (int h = 0; h < 4; ++h) {
          float4 a = ((const float4*)zsrc)[2*h], b4 = ((const float4*)zsrc)[2*h+1];
          uint4 wv;
          wv.x = (u32)f2bf(a.x)  | ((u32)f2bf(a.y)  << 16);
          wv.y = (u32)f2bf(a.z)  | ((u32)f2bf(a.w)  << 16);
          wv.z = (u32)f2bf(b4.x) | ((u32)f2bf(b4.y) << 16);
          wv.w = (u32)f2bf(b4.z) | ((u32)f2bf(b4.w) << 16);
          *(uint4*)&cmfrag[((mt_r*8 + q)*64 + r15 + 16*h)*8] = wv;
        }
      }
      #pragma unroll
      for (int u = 0; u < 8; ++u) {
        int idx = tid + u*256;
        int c = idx >> 3, rr = idx & 7;
        fgAs[(c>>5)*264 + (c&31)*8 + rr] = fgA[t*2048 + idx];
      }
      #pragma unroll
      for (int u = 0; u < 8; ++u) {
        int idx = tid + u*256;
        int rr = idx >> 8, c = idx & 255;
        fgBs[rr*288 + (c>>5)*36 + (c&31)] = fgB[t*2048 + idx];
      }
      {
        int e = tid >> 6, c = tid & 63, half = c >> 5, cl = c & 31;
        smallw[(e*2 + half)*36 + cl] = tgW2[t*256 + c*4 + e];
      }
      __syncthreads();   // A

      // ---------- feature gate (in-place on cmfrag): racc = cm_pre @ fg_A, gate, repack ----------
      {
        u32 zz[16];
        #pragma unroll
        for (int h = 0; h < 4; ++h) {
          uint4 wv = *(const uint4*)&cmfrag[((mt_r*8 + q)*64 + r15 + 16*h)*8];
          zz[4*h] = wv.x; zz[4*h+1] = wv.y; zz[4*h+2] = wv.z; zz[4*h+3] = wv.w;
        }
        float acc[8];
        #pragma unroll
        for (int rr = 0; rr < 8; ++rr) acc[rr] = 0.f;
        const float* Ap = fgAs + q*264;
        #pragma unroll
        for (int jf = 0; jf < 8; ++jf) {
          u32 p0 = zz[2*jf], p1 = zz[2*jf+1];
          float zc[4] = { bf2f((u16)p0), bf2f((u16)(p0>>16)), bf2f((u16)p1), bf2f((u16)(p1>>16)) };
          #pragma unroll
          for (int u = 0; u < 4; ++u) {
            const float4* ar = (const float4*)(Ap + (jf*4 + u)*8);
            float4 lo = ar[0], hi = ar[1];
            acc[0] += zc[u]*lo.x; acc[1] += zc[u]*lo.y; acc[2] += zc[u]*lo.z; acc[3] += zc[u]*lo.w;
            acc[4] += zc[u]*hi.x; acc[5] += zc[u]*hi.y; acc[6] += zc[u]*hi.z; acc[7] += zc[u]*hi.w;
          }
        }
        #pragma unroll
        for (int rr = 0; rr < 8; ++rr) {
          acc[rr] += __shfl_xor(acc[rr], 1);
          acc[rr] += __shfl_xor(acc[rr], 2);
          acc[rr] += __shfl_xor(acc[rr], 4);
        }
        #pragma unroll
        for (int h = 0; h < 4; ++h) {
          u16 pk8[8];
          #pragma unroll
          for (int half = 0; half < 2; ++half) {
            const float* bp = fgBs + q*36 + h*8 + half*4;
            float l0=0.f, l1=0.f, l2=0.f, l3=0.f;
            #pragma unroll
            for (int rr = 0; rr < 8; ++rr) {
              float4 b4 = *(const float4*)(bp + rr*288);
              l0 += acc[rr]*b4.x; l1 += acc[rr]*b4.y; l2 += acc[rr]*b4.z; l3 += acc[rr]*b4.w;
            }
            int zi = h*4 + half*2;
            u32 p0 = zz[zi], p1 = zz[zi+1];
            float zv[4] = { bf2f((u16)p0), bf2f((u16)(p0>>16)), bf2f((u16)p1), bf2f((u16)(p1>>16)) };
            float lg[4] = { l0, l1, l2, l3 };
            #pragma unroll
            for (int u = 0; u < 4; ++u) {
              float gate = 2.f / (1.f + __expf(-lg[u]));
              pk8[half*4 + u] = f2bf(zv[u] * gate);
            }
          }
          uint4 wv;
          wv.x = (u32)pk8[0] | ((u32)pk8[1] << 16);
          wv.y = (u32)pk8[2] | ((u32)pk8[3] << 16);
          wv.z = (u32)pk8[4] | ((u32)pk8[5] << 16);
          wv.w = (u32)pk8[6] | ((u32)pk8[7] << 16);
          *(uint4*)&cmfrag[((mt_r*8 + q)*64 + r15 + 16*h)*8] = wv;
        }
      }
      __syncthreads();   // B

      // ---------- task gate layer1: gh = swish(cm @ tg_W1 + b); wave w owns n-tile w ----------
      {
        f32x4 accg[2] = { fz, fz };
        const u16* wp = pk + OFF_TG + ((t*4 + wid)*8)*512 + lane*8;
        #pragma unroll
        for (int kt = 0; kt < 8; ++kt) {
          bf16x8 bfr = ld_frag(wp + kt*512);
          #pragma unroll
          for (int mt = 0; mt < 2; ++mt) {
            bf16x8 afr = ld_frag(&cmfrag[((mt*8 + kt)*64 + lane)*8]);
            accg[mt] = mfma16(afr, bfr, accg[mt]);
          }
        }
        int colg = wid*16 + l15;
        float bias = tgb1[t*64 + colg];
        #pragma unroll
        for (int mt = 0; mt < 2; ++mt)
          #pragma unroll
          for (int rr = 0; rr < 4; ++rr)
            fbuf[(mt*16 + rl + rr)*72 + colg] = swishf(accg[mt][rr] + bias);
      }
      __syncthreads();   // C

      // ---------- task gate layer2 + softmax (lanes q,q+4 split the 64-dim dot) ----------
      {
        int e = q & 3, half = q >> 2;
        float part = 0.f;
        #pragma unroll
        for (int cj = 0; cj < 8; ++cj) {
          float4 g4 = *(const float4*)&fbuf[r*72 + half*32 + cj*4];
          float4 w4 = *(const float4*)&smallw[(e*2 + half)*36 + cj*4];
          part += g4.x*w4.x + g4.y*w4.y + g4.z*w4.z + g4.w*w4.w;
        }
        part += __shfl_xor(part, 4);
        float logit = part + tgb2[t*4 + e];
        float mx = fmaxf(logit, __shfl_xor(logit, 1));
        mx = fmaxf(mx, __shfl_xor(mx, 2));
        float ex = __expf(logit - mx);
        float sm = ex + __shfl_xor(ex, 1);
        sm += __shfl_xor(sm, 2);
        if (q < 4) gwbuf[r*4 + q] = ex / sm;
      }
      // NO barrier: gwbuf's first reader (LN, el=0) is 3 barriers (E1,E2,E3) downstream;
      // GEMM1 touches only cmfrag (stable) + h1frag (fgBs last read was above, pre-E1).

      // ---------- expert loop ----------
      float agg[8];
      #pragma unroll
      for (int c = 0; c < 8; ++c) agg[c] = 0.f;

      #pragma unroll 1
      for (int el = 0; el < 4; ++el) {
        const int ei = (el < 2) ? el : (el + 2*g);

        // GEMM1: cm(32x256) @ W1(256x128); wave owns n-tiles 2w,2w+1
        f32x4 acc1[2][2];
        #pragma unroll
        for (int mt = 0; mt < 2; ++mt) { acc1[mt][0] = fz; acc1[mt][1] = fz; }
        {
          const u16* w1p = pk + ((ei*8 + 2*wid)*8)*512 + lane*8;
          #pragma unroll
          for (int kt = 0; kt < 8; ++kt) {
            bf16x8 b0 = ld_frag(w1p + kt*512);
            bf16x8 b1 = ld_frag(w1p + 4096 + kt*512);
            #pragma unroll
            for (int mt = 0; mt < 2; ++mt) {
              bf16x8 a = ld_frag(&cmfrag[((mt*8 + kt)*64 + lane)*8]);
              acc1[mt][0] = mfma16(a, b0, acc1[mt][0]);
              acc1[mt][1] = mfma16(a, b1, acc1[mt][1]);
            }
          }
        }
        #pragma unroll
        for (int nn = 0; nn < 2; ++nn) {
          int col = (2*wid + nn)*16 + l15;
          float bias = eb1[ei*128 + col];
          int kt2 = col >> 5, h2 = (col >> 3) & 3, i2 = col & 7;
          #pragma unroll
          for (int mt = 0; mt < 2; ++mt)
            #pragma unroll
            for (int rr = 0; rr < 4; ++rr)
              h1frag[((mt*4 + kt2)*64 + rl + rr + 16*h2)*8 + i2] = f2bf(swishf(acc1[mt][nn][rr] + bias));
        }
        __syncthreads();  // E1

        // GEMM2: h1(32x128) @ W2(128x64); wave owns n-tile w
        f32x4 acc2[2] = { fz, fz };
        {
          const u16* w2p = pk + OFF_W2 + ((ei*4 + wid)*4)*512 + lane*8;
          #pragma unroll
          for (int kt = 0; kt < 4; ++kt) {
            bf16x8 b0 = ld_frag(w2p + kt*512);
            #pragma unroll
            for (int mt = 0; mt < 2; ++mt) {
              bf16x8 a = ld_frag(&h1frag[((mt*4 + kt)*64 + lane)*8]);
              acc2[mt] = mfma16(a, b0, acc2[mt]);
            }
          }
        }
        {
          int col = wid*16 + l15;
          float bias = eb2[ei*64 + col];
          int kt2 = col >> 5, h2 = (col >> 3) & 3, i2 = col & 7;
          #pragma unroll
          for (int mt = 0; mt < 2; ++mt)
            #pragma unroll
            for (int rr = 0; rr < 4; ++rr)
              h2frag[((mt*2 + kt2)*64 + rl + rr + 16*h2)*8 + i2] = f2bf(swishf(acc2[mt][rr] + bias));
        }
        __syncthreads();  // E2

        // GEMM3: h2(32x64) @ W3(64x64) -> e_pre into fbuf
        f32x4 acc3[2] = { fz, fz };
        {
          const u16* w3p = pk + OFF_W3 + ((ei*4 + wid)*2)*512 + lane*8;
          #pragma unroll
          for (int kt = 0; kt < 2; ++kt) {
            bf16x8 b0 = ld_frag(w3p + kt*512);
            #pragma unroll
            for (int mt = 0; mt < 2; ++mt) {
              bf16x8 a = ld_frag(&h2frag[((mt*2 + kt)*64 + lane)*8]);
              acc3[mt] = mfma16(a, b0, acc3[mt]);
            }
          }
        }
        {
          int col = wid*16 + l15;
          float bias = eb3[ei*64 + col];
          #pragma unroll
          for (int mt = 0; mt < 2; ++mt)
            #pragma unroll
            for (int rr = 0; rr < 4; ++rr)
              fbuf[(mt*16 + rl + rr)*72 + col] = acc3[mt][rr] + bias;
        }
        __syncthreads();  // E3

        // LayerNorm + self-gate diag + weighted aggregate (thread (r,q): 8 cols of row r)
        {
          float v[8];
          float4 fa = *(const float4*)&fbuf[r*72 + q*8];
          float4 fb = *(const float4*)&fbuf[r*72 + q*8 + 4];
          v[0]=fa.x; v[1]=fa.y; v[2]=fa.z; v[3]=fa.w;
          v[4]=fb.x; v[5]=fb.y; v[6]=fb.z; v[7]=fb.w;
          float s1 = 0.f;
          #pragma unroll
          for (int c = 0; c < 8; ++c) s1 += v[c];
          s1 += __shfl_xor(s1, 1); s1 += __shfl_xor(s1, 2); s1 += __shfl_xor(s1, 4);
          float mu = s1 * (1.f/64.f);
          float s2 = 0.f;
          #pragma unroll
          for (int c = 0; c < 8; ++c) { float d = v[c] - mu; s2 += d*d; }
          s2 += __shfl_xor(s2, 1); s2 += __shfl_xor(s2, 2); s2 += __shfl_xor(s2, 4);
          float rs = rsqrtf(s2 * (1.f/64.f) + 1e-5f);
          const float* lsp = lns + ei*64 + q*8;
          const float* lbp = lnb + ei*64 + q*8;
          const float* sgp = sgW + (t*64 + q*8)*4 + el;
          float swp = 0.f;
          #pragma unroll
          for (int c = 0; c < 8; ++c) {
            float eh = (v[c] - mu) * rs * lsp[c] + lbp[c];
            v[c] = eh;
            swp += eh * sgp[c*4];
          }
          swp += __shfl_xor(swp, 1); swp += __shfl_xor(swp, 2); swp += __shfl_xor(swp, 4);
          swp += sgb[t*4 + el];
          float fac = swp * gwbuf[r*4 + el];
          #pragma unroll
          for (int c = 0; c < 8; ++c) agg[c] += v[c] * fac;
        }
      }  // expert loop

      // ---------- tower via MFMA: agg(32x64) @ W1(64x64) -> swish -> @ W2(64x32) -> swish -> @ w3 ----------
      {
        uint4 wv;
        wv.x = (u32)f2bf(agg[0]) | ((u32)f2bf(agg[1]) << 16);
        wv.y = (u32)f2bf(agg[2]) | ((u32)f2bf(agg[3]) << 16);
        wv.z = (u32)f2bf(agg[4]) | ((u32)f2bf(agg[5]) << 16);
        wv.w = (u32)f2bf(agg[6]) | ((u32)f2bf(agg[7]) << 16);
        *(uint4*)&aggfrag[((mt_r*2 + (q>>2))*64 + r15 + 16*(q&3)) * 8] = wv;
      }
      __syncthreads();  // F

      {
        // T1: wave w owns n-tile w of 64
        f32x4 at1[2] = { fz, fz };
        const u16* tw1p = pk + OFF_TW1 + ((t*4 + wid)*2)*512 + lane*8;
        #pragma unroll
        for (int kt = 0; kt < 2; ++kt) {
          bf16x8 b0 = ld_frag(tw1p + kt*512);
          #pragma unroll
          for (int mt = 0; mt < 2; ++mt) {
            bf16x8 a = ld_frag(&aggfrag[((mt*2 + kt)*64 + lane)*8]);
            at1[mt] = mfma16(a, b0, at1[mt]);
          }
        }
        int colT = wid*16 + l15;
        float bias = twb1[t*64 + colT];
        int ktT = colT >> 5, hT = (colT >> 3) & 3, iT = colT & 7;
        #pragma unroll
        for (int mt = 0; mt < 2; ++mt)
          #pragma unroll
          for (int rr = 0; rr < 4; ++rr)
            th1frag[((mt*2 + ktT)*64 + rl + rr + 16*hT)*8 + iT] = f2bf(swishf(at1[mt][rr] + bias));
      }
      __syncthreads();  // G

      if (wid < 2) {
        // T2: waves 0,1 own the two 16-col tiles of 32
        f32x4 at2[2] = { fz, fz };
        const u16* tw2p = pk + OFF_TW2 + ((t*2 + wid)*2)*512 + lane*8;
        #pragma unroll
        for (int kt = 0; kt < 2; ++kt) {
          bf16x8 b0 = ld_frag(tw2p + kt*512);
          #pragma unroll
          for (int mt = 0; mt < 2; ++mt) {
            bf16x8 a = ld_frag(&th1frag[((mt*2 + kt)*64 + lane)*8]);
            at2[mt] = mfma16(a, b0, at2[mt]);
          }
        }
        int colU = wid*16 + l15;
        float b2  = twb2[t*32 + colU];
        float w3v = twW3[t*32 + colU];
        float px[8];
        #pragma unroll
        for (int mt = 0; mt < 2; ++mt)
          #pragma unroll
          for (int rr = 0; rr < 4; ++rr)
            px[mt*4 + rr] = swishf(at2[mt][rr] + b2) * w3v;
        #pragma unroll
        for (int k = 0; k < 8; ++k) {
          px[k] += __shfl_xor(px[k], 1);
          px[k] += __shfl_xor(px[k], 2);
          px[k] += __shfl_xor(px[k], 4);
          px[k] += __shfl_xor(px[k], 8);
        }
        if (l15 == 0) {
          #pragma unroll
          for (int mt = 0; mt < 2; ++mt)
            #pragma unroll
            for (int rr = 0; rr < 4; ++rr)
              arrp[wid*32 + mt*16 + rl + rr] = px[mt*4 + rr];
        }
      }
      __syncthreads();  // H

      if (tid < 32) {
        float x = arrp[tid] + arrp[32 + tid] + twb3[t];
        out[(size_t)(rowBase + tid)*4 + t] = 1.f / (1.f + __expf(-x));
      }
      // NO barrier I: next sub's staging writes cmfrag/fgAs/fgBs/smallw; their last
      // readers (GEMM1 el=3, softmax, T2 via th1frag alias) all complete before H.
      // arrp (gwbuf alias) readers above are tid<32 only, and its next writer is the
      // next sub's softmax, which is beyond barriers A,B,C.
    }
  }
}

extern "C" void kernel_launch(void* const* d_in, const int* in_sizes, int n_in,
                              void* d_out, int out_size, void* d_ws, size_t ws_size,
                              hipStream_t stream)
{
  (void)in_sizes; (void)n_in; (void)out_size; (void)ws_size;
  const float* zs   = (const float*)d_in[0];
  const float* zg0  = (const float*)d_in[1];
  const float* zg1  = (const float*)d_in[2];
  // d_in[3] = v : unused by the reference
  const float* eW1  = (const float*)d_in[4];
  const float* eb1  = (const float*)d_in[5];
  const float* eW2  = (const float*)d_in[6];
  const float* eb2  = (const float*)d_in[7];
  const float* eW3  = (const float*)d_in[8];
  const float* eb3  = (const float*)d_in[9];
  const float* lns  = (const float*)d_in[10];
  const float* lnb  = (const float*)d_in[11];
  const float* fgA  = (const float*)d_in[12];
  const float* fgB  = (const float*)d_in[13];
  const float* tgW1 = (const float*)d_in[14];
  const float* tgb1 = (const float*)d_in[15];
  const float* tgW2 = (const float*)d_in[16];
  const float* tgb2 = (const float*)d_in[17];
  const float* sgW  = (const float*)d_in[18];
  const float* sgb  = (const float*)d_in[19];
  const float* twW1 = (const float*)d_in[20];
  const float* twb1 = (const float*)d_in[21];
  const float* twW2 = (const float*)d_in[22];
  const float* twb2 = (const float*)d_in[23];
  const float* twW3 = (const float*)d_in[24];
  const float* twb3 = (const float*)d_in[25];

  u16* pkw = (u16*)d_ws;          // needs 720896 B
  float* outp = (float*)d_out;

  prep_pack<<<(NPACK + 255)/256, 256, 0, stream>>>(eW1, eW2, eW3, tgW1, twW1, twW2, pkw);
  home_main<<<65536/32, 256, 0, stream>>>(zs, zg0, zg1, fgA, fgB, tgW2, tgb1, tgb2,
      eb1, eb2, eb3, lns, lnb, sgW, sgb, twb1, twb2, twW3, twb3,
      pkw, outp);
}